// Round 1
// baseline (660.467 us; speedup 1.0000x reference)
//
#include <hip/hip_runtime.h>
#include <hip/hip_bf16.h>
#include <stdint.h>

#define N_NODES 20000
#define N_EDGES 640000
#define DIM 128

using bf16x8 = __attribute__((ext_vector_type(8))) short;
using f32x4  = __attribute__((ext_vector_type(4))) float;

static __device__ __forceinline__ unsigned short f2bf(float f) {
    union { float f; unsigned int u; } v; v.f = f;
    unsigned int r = v.u + 0x7FFFu + ((v.u >> 16) & 1u);
    return (unsigned short)(r >> 16);
}

// ---------------- prep: bf16 node table, transposed bf16 weights, zero counts ----------------
__global__ void prep_kernel(const float* __restrict__ node_feat,
                            const float* __restrict__ W1e, const float* __restrict__ W2e,
                            const float* __restrict__ W1n, const float* __restrict__ W2n,
                            unsigned short* __restrict__ node_bf,
                            unsigned short* __restrict__ Wt1e, unsigned short* __restrict__ Wt2e,
                            unsigned short* __restrict__ Wt1n, unsigned short* __restrict__ Wt2n,
                            int* __restrict__ counts) {
    int tid = blockIdx.x * blockDim.x + threadIdx.x;
    int stride = gridDim.x * blockDim.x;
    for (int i = tid; i < N_NODES * DIM; i += stride) node_bf[i] = f2bf(node_feat[i]);
    // Wt[n][k] = W[k][n]
    for (int i = tid; i < DIM * 384; i += stride) { int n = i / 384, k = i % 384; Wt1e[i] = f2bf(W1e[k * DIM + n]); }
    for (int i = tid; i < DIM * DIM; i += stride) { int n = i / DIM, k = i % DIM; Wt2e[i] = f2bf(W2e[k * DIM + n]); }
    for (int i = tid; i < DIM * 256; i += stride) { int n = i / 256, k = i % 256; Wt1n[i] = f2bf(W1n[k * DIM + n]); }
    for (int i = tid; i < DIM * DIM; i += stride) { int n = i / DIM, k = i % DIM; Wt2n[i] = f2bf(W2n[k * DIM + n]); }
    for (int i = tid; i < N_NODES; i += stride) counts[i] = 0;
}

// ---------------- CSR build ----------------
__global__ void count_kernel(const int* __restrict__ eidx, int* __restrict__ counts) {
    int e = blockIdx.x * blockDim.x + threadIdx.x;
    if (e < N_EDGES) atomicAdd(&counts[eidx[N_EDGES + e]], 1);
}

__global__ void scan_kernel(const int* __restrict__ counts, int* __restrict__ offsets,
                            int* __restrict__ cursor) {
    __shared__ int tmp[1024];
    __shared__ int carry;
    int tid = threadIdx.x;
    if (tid == 0) carry = 0;
    __syncthreads();
    for (int base = 0; base < N_NODES; base += 1024) {
        int i = base + tid;
        int v = (i < N_NODES) ? counts[i] : 0;
        tmp[tid] = v;
        __syncthreads();
        #pragma unroll
        for (int off = 1; off < 1024; off <<= 1) {
            int t = (tid >= off) ? tmp[tid - off] : 0;
            __syncthreads();
            tmp[tid] += t;
            __syncthreads();
        }
        int excl = tmp[tid] - v;
        int c = carry;
        if (i < N_NODES) { offsets[i] = excl + c; cursor[i] = excl + c; }
        __syncthreads();
        if (tid == 0) carry = c + tmp[1023];
        __syncthreads();
    }
}

__global__ void scatter_kernel(const int* __restrict__ eidx, int* __restrict__ cursor,
                               int* __restrict__ elist) {
    int e = blockIdx.x * blockDim.x + threadIdx.x;
    if (e < N_EDGES) {
        int p = atomicAdd(&cursor[eidx[N_EDGES + e]], 1);
        elist[p] = e;
    }
}

// ---------------- edge MLP: out_edge = edge_feat + MLP([edge_feat, n[src], n[dst]]) ----------------
// block = 256 threads = 4 waves; wave handles 64 rows (4 row-tiles of 16); block = 256 edges.
__launch_bounds__(256, 2)
__global__ void edge_kernel(const float* __restrict__ edge_feat,
                            const int* __restrict__ eidx,
                            const unsigned short* __restrict__ node_bf,
                            const unsigned short* __restrict__ Wt1e,
                            const unsigned short* __restrict__ Wt2e,
                            const float* __restrict__ b1e,
                            const float* __restrict__ b2e,
                            float* __restrict__ out_edge) {
    __shared__ unsigned short lds_h[256 * DIM];   // 64 KB, swizzled
    const int tid = threadIdx.x;
    const int wv = tid >> 6;
    const int l = tid & 63;
    const int lr = l & 15;
    const int kg = l >> 4;

    const int eBase = blockIdx.x * 256;

    int e[4], se[4], de[4];
    #pragma unroll
    for (int rt = 0; rt < 4; ++rt) {
        int row = wv * 64 + rt * 16 + lr;
        e[rt] = eBase + row;
        se[rt] = eidx[e[rt]];
        de[rt] = eidx[N_EDGES + e[rt]];
    }

    float b1r[8], b2r[8];
    #pragma unroll
    for (int t = 0; t < 8; ++t) { b1r[t] = b1e[t * 16 + lr]; b2r[t] = b2e[t * 16 + lr]; }

    f32x4 acc[4][8];
    #pragma unroll
    for (int rt = 0; rt < 4; ++rt)
        #pragma unroll
        for (int t = 0; t < 8; ++t) acc[rt][t] = (f32x4){0.f, 0.f, 0.f, 0.f};

    // GEMM1: K = 384 (12 steps of 32)
    #pragma unroll
    for (int s = 0; s < 12; ++s) {
        const int kk = s * 32 + kg * 8;
        bf16x8 A[4];
        if (s < 4) {
            #pragma unroll
            for (int rt = 0; rt < 4; ++rt) {
                const float* p = edge_feat + (long)e[rt] * DIM + kk;
                float4 f0 = *(const float4*)p;
                float4 f1 = *(const float4*)(p + 4);
                bf16x8 a;
                a[0] = (short)f2bf(f0.x); a[1] = (short)f2bf(f0.y);
                a[2] = (short)f2bf(f0.z); a[3] = (short)f2bf(f0.w);
                a[4] = (short)f2bf(f1.x); a[5] = (short)f2bf(f1.y);
                a[6] = (short)f2bf(f1.z); a[7] = (short)f2bf(f1.w);
                A[rt] = a;
            }
        } else if (s < 8) {
            #pragma unroll
            for (int rt = 0; rt < 4; ++rt)
                A[rt] = *(const bf16x8*)(node_bf + (long)se[rt] * DIM + (kk - 128));
        } else {
            #pragma unroll
            for (int rt = 0; rt < 4; ++rt)
                A[rt] = *(const bf16x8*)(node_bf + (long)de[rt] * DIM + (kk - 256));
        }
        #pragma unroll
        for (int t = 0; t < 8; ++t) {
            bf16x8 B = *(const bf16x8*)(Wt1e + (t * 16 + lr) * 384 + kk);
            #pragma unroll
            for (int rt = 0; rt < 4; ++rt)
                acc[rt][t] = __builtin_amdgcn_mfma_f32_16x16x32_bf16(A[rt], B, acc[rt][t], 0, 0, 0);
        }
    }

    // epilogue 1: silu -> LDS (swizzled)
    #pragma unroll
    for (int rt = 0; rt < 4; ++rt) {
        int rowb = wv * 64 + rt * 16 + kg * 4;
        #pragma unroll
        for (int t = 0; t < 8; ++t) {
            int col = t * 16 + lr;
            #pragma unroll
            for (int r = 0; r < 4; ++r) {
                int row = rowb + r;
                float x = acc[rt][t][r] + b1r[t];
                float h = x / (1.0f + __expf(-x));
                int byte = (row * 256 + col * 2) ^ ((row & 7) << 4);
                *(unsigned short*)((char*)lds_h + byte) = f2bf(h);
            }
        }
    }
    __syncthreads();

    // GEMM2: K = 128 (4 steps)
    f32x4 acc2[4][8];
    #pragma unroll
    for (int rt = 0; rt < 4; ++rt)
        #pragma unroll
        for (int t = 0; t < 8; ++t) acc2[rt][t] = (f32x4){0.f, 0.f, 0.f, 0.f};

    #pragma unroll
    for (int s = 0; s < 4; ++s) {
        const int kk = s * 32 + kg * 8;
        bf16x8 A[4];
        #pragma unroll
        for (int rt = 0; rt < 4; ++rt) {
            int row = wv * 64 + rt * 16 + lr;
            int byte = (row * 256 + kk * 2) ^ ((row & 7) << 4);
            A[rt] = *(const bf16x8*)((const char*)lds_h + byte);
        }
        #pragma unroll
        for (int t = 0; t < 8; ++t) {
            bf16x8 B = *(const bf16x8*)(Wt2e + (t * 16 + lr) * DIM + kk);
            #pragma unroll
            for (int rt = 0; rt < 4; ++rt)
                acc2[rt][t] = __builtin_amdgcn_mfma_f32_16x16x32_bf16(A[rt], B, acc2[rt][t], 0, 0, 0);
        }
    }

    // epilogue 2: residual + bias -> out
    #pragma unroll
    for (int rt = 0; rt < 4; ++rt) {
        #pragma unroll
        for (int t = 0; t < 8; ++t) {
            int col = t * 16 + lr;
            #pragma unroll
            for (int r = 0; r < 4; ++r) {
                int row = wv * 64 + rt * 16 + kg * 4 + r;
                long idx = (long)(eBase + row) * DIM + col;
                out_edge[idx] = edge_feat[idx] + acc2[rt][t][r] + b2r[t];
            }
        }
    }
}

// ---------------- mean aggregation (CSR pull) ----------------
__global__ void agg_kernel(const float* __restrict__ edge_out,
                           const int* __restrict__ offsets, const int* __restrict__ counts,
                           const int* __restrict__ elist,
                           unsigned short* __restrict__ agg_bf) {
    int n = blockIdx.x * 4 + (threadIdx.x >> 6);
    int l = threadIdx.x & 63;
    if (n >= N_NODES) return;
    int off = offsets[n], cnt = counts[n];
    float a0 = 0.f, a1 = 0.f;
    for (int i = 0; i < cnt; ++i) {
        int e = elist[off + i];
        const float2 v = *(const float2*)(edge_out + (long)e * DIM + l * 2);
        a0 += v.x; a1 += v.y;
    }
    float inv = 1.0f / fmaxf((float)cnt, 1.0f);
    agg_bf[n * DIM + l * 2] = f2bf(a0 * inv);
    agg_bf[n * DIM + l * 2 + 1] = f2bf(a1 * inv);
}

// ---------------- node MLP: out_node = node_feat + MLP([node_feat, agg]) ----------------
__launch_bounds__(256, 2)
__global__ void node_kernel(const float* __restrict__ node_feat,
                            const unsigned short* __restrict__ node_bf,
                            const unsigned short* __restrict__ agg_bf,
                            const unsigned short* __restrict__ Wt1n,
                            const unsigned short* __restrict__ Wt2n,
                            const float* __restrict__ b1n,
                            const float* __restrict__ b2n,
                            float* __restrict__ out_node) {
    __shared__ unsigned short lds_h[256 * DIM];
    const int tid = threadIdx.x;
    const int wv = tid >> 6;
    const int l = tid & 63;
    const int lr = l & 15;
    const int kg = l >> 4;

    const int nBase = blockIdx.x * 256;

    int rowc[4];
    #pragma unroll
    for (int rt = 0; rt < 4; ++rt) {
        int row = nBase + wv * 64 + rt * 16 + lr;
        rowc[rt] = row < N_NODES ? row : N_NODES - 1;
    }

    float b1r[8], b2r[8];
    #pragma unroll
    for (int t = 0; t < 8; ++t) { b1r[t] = b1n[t * 16 + lr]; b2r[t] = b2n[t * 16 + lr]; }

    f32x4 acc[4][8];
    #pragma unroll
    for (int rt = 0; rt < 4; ++rt)
        #pragma unroll
        for (int t = 0; t < 8; ++t) acc[rt][t] = (f32x4){0.f, 0.f, 0.f, 0.f};

    // GEMM1: K = 256 (8 steps)
    #pragma unroll
    for (int s = 0; s < 8; ++s) {
        const int kk = s * 32 + kg * 8;
        bf16x8 A[4];
        if (s < 4) {
            #pragma unroll
            for (int rt = 0; rt < 4; ++rt)
                A[rt] = *(const bf16x8*)(node_bf + (long)rowc[rt] * DIM + kk);
        } else {
            #pragma unroll
            for (int rt = 0; rt < 4; ++rt)
                A[rt] = *(const bf16x8*)(agg_bf + (long)rowc[rt] * DIM + (kk - 128));
        }
        #pragma unroll
        for (int t = 0; t < 8; ++t) {
            bf16x8 B = *(const bf16x8*)(Wt1n + (t * 16 + lr) * 256 + kk);
            #pragma unroll
            for (int rt = 0; rt < 4; ++rt)
                acc[rt][t] = __builtin_amdgcn_mfma_f32_16x16x32_bf16(A[rt], B, acc[rt][t], 0, 0, 0);
        }
    }

    #pragma unroll
    for (int rt = 0; rt < 4; ++rt) {
        int rowb = wv * 64 + rt * 16 + kg * 4;
        #pragma unroll
        for (int t = 0; t < 8; ++t) {
            int col = t * 16 + lr;
            #pragma unroll
            for (int r = 0; r < 4; ++r) {
                int row = rowb + r;
                float x = acc[rt][t][r] + b1r[t];
                float h = x / (1.0f + __expf(-x));
                int byte = (row * 256 + col * 2) ^ ((row & 7) << 4);
                *(unsigned short*)((char*)lds_h + byte) = f2bf(h);
            }
        }
    }
    __syncthreads();

    f32x4 acc2[4][8];
    #pragma unroll
    for (int rt = 0; rt < 4; ++rt)
        #pragma unroll
        for (int t = 0; t < 8; ++t) acc2[rt][t] = (f32x4){0.f, 0.f, 0.f, 0.f};

    #pragma unroll
    for (int s = 0; s < 4; ++s) {
        const int kk = s * 32 + kg * 8;
        bf16x8 A[4];
        #pragma unroll
        for (int rt = 0; rt < 4; ++rt) {
            int row = wv * 64 + rt * 16 + lr;
            int byte = (row * 256 + kk * 2) ^ ((row & 7) << 4);
            A[rt] = *(const bf16x8*)((const char*)lds_h + byte);
        }
        #pragma unroll
        for (int t = 0; t < 8; ++t) {
            bf16x8 B = *(const bf16x8*)(Wt2n + (t * 16 + lr) * DIM + kk);
            #pragma unroll
            for (int rt = 0; rt < 4; ++rt)
                acc2[rt][t] = __builtin_amdgcn_mfma_f32_16x16x32_bf16(A[rt], B, acc2[rt][t], 0, 0, 0);
        }
    }

    #pragma unroll
    for (int rt = 0; rt < 4; ++rt) {
        #pragma unroll
        for (int t = 0; t < 8; ++t) {
            int col = t * 16 + lr;
            #pragma unroll
            for (int r = 0; r < 4; ++r) {
                int row = nBase + wv * 64 + rt * 16 + kg * 4 + r;
                if (row < N_NODES) {
                    long idx = (long)row * DIM + col;
                    out_node[idx] = node_feat[idx] + acc2[rt][t][r] + b2r[t];
                }
            }
        }
    }
}

extern "C" void kernel_launch(void* const* d_in, const int* in_sizes, int n_in,
                              void* d_out, int out_size, void* d_ws, size_t ws_size,
                              hipStream_t stream) {
    const float* node_feat = (const float*)d_in[0];
    const float* edge_feat = (const float*)d_in[1];
    const int*   eidx      = (const int*)d_in[2];
    const float* W1e = (const float*)d_in[3];
    const float* b1e = (const float*)d_in[4];
    const float* W2e = (const float*)d_in[5];
    const float* b2e = (const float*)d_in[6];
    const float* W1n = (const float*)d_in[7];
    const float* b1n = (const float*)d_in[8];
    const float* W2n = (const float*)d_in[9];
    const float* b2n = (const float*)d_in[10];

    char* ws = (char*)d_ws;
    size_t off = 0;
    auto alloc = [&](size_t bytes) {
        void* p = ws + off;
        off += (bytes + 255) & ~(size_t)255;
        return p;
    };
    unsigned short* node_bf = (unsigned short*)alloc((size_t)N_NODES * DIM * 2);
    unsigned short* agg_bf  = (unsigned short*)alloc((size_t)N_NODES * DIM * 2);
    unsigned short* Wt1e    = (unsigned short*)alloc((size_t)DIM * 384 * 2);
    unsigned short* Wt2e    = (unsigned short*)alloc((size_t)DIM * DIM * 2);
    unsigned short* Wt1n    = (unsigned short*)alloc((size_t)DIM * 256 * 2);
    unsigned short* Wt2n    = (unsigned short*)alloc((size_t)DIM * DIM * 2);
    int* counts  = (int*)alloc((size_t)N_NODES * 4);
    int* offsets = (int*)alloc((size_t)N_NODES * 4);
    int* cursor  = (int*)alloc((size_t)N_NODES * 4);
    int* elist   = (int*)alloc((size_t)N_EDGES * 4);

    float* out_node = (float*)d_out;
    float* out_edge = out_node + (size_t)N_NODES * DIM;

    prep_kernel<<<512, 256, 0, stream>>>(node_feat, W1e, W2e, W1n, W2n,
                                         node_bf, Wt1e, Wt2e, Wt1n, Wt2n, counts);
    count_kernel<<<(N_EDGES + 255) / 256, 256, 0, stream>>>(eidx, counts);
    scan_kernel<<<1, 1024, 0, stream>>>(counts, offsets, cursor);
    scatter_kernel<<<(N_EDGES + 255) / 256, 256, 0, stream>>>(eidx, cursor, elist);
    edge_kernel<<<N_EDGES / 256, 256, 0, stream>>>(edge_feat, eidx, node_bf, Wt1e, Wt2e,
                                                   b1e, b2e, out_edge);
    agg_kernel<<<(N_NODES + 3) / 4, 256, 0, stream>>>(out_edge, offsets, counts, elist, agg_bf);
    node_kernel<<<(N_NODES + 255) / 256, 256, 0, stream>>>(node_feat, node_bf, agg_bf,
                                                           Wt1n, Wt2n, b1n, b2n, out_node);
}